// Round 9
// baseline (46.275 us; speedup 1.0000x reference)
//
#include <hip/hip_runtime.h>
#include <math.h>

// YOLOv3 detection-head decode — barrier-free, LDS-free.
// prediction: [B=32, 255, 52, 52] f32 ; anchors: [3,2] f32
// out: [B, 52*52*3, 85] f32 ; per (b,gj) slice output = 13,260 contiguous
// floats, e = gi*255 + c (c = a*85+attr).
//
// Key idea: no LDS transpose needed. Lane loads float4 = in[c][gi..gi+3]
// (16B aligned, row-exclusive). Its 4 values go to out addresses
// k*255 + c (k=0..3): for fixed k, c is consecutive across lanes -> each
// scalar store is a contiguous 256B wave store. L2 write-back merges the
// interleaved wave streams into full lines. Per-c attr decode computed once
// per lane-iter (shared by 4 elements). Zero barriers, zero LDS -> waves
// fully independent, no convoy; 16B-granule loads sector-share via L1
// (a block's 4 waves cover each 64B sector exactly).
//
// Block = (slice, chunk{16,16,16,4} gi); wave w owns 4 gi (or 1 for chunk 3).
// XCD swizzle keeps a slice's chunks on one XCD (L2-shared sector edges).

#define BB 32
#define GG 52
#define NROWS 255
#define PLANE (GG * GG)        // 2704
#define SLICE_N (GG * NROWS)   // 13260
#define L2E 1.442695040889f

typedef float f32x4 __attribute__((ext_vector_type(4)));

__device__ __forceinline__ float fast_sigmoid(float x) {
    return __builtin_amdgcn_rcpf(1.0f + __builtin_amdgcn_exp2f(-L2E * x));
}

template<int NGW>   // gi owned per wave: 4 (bulk) or 1 (tail chunk)
__device__ __forceinline__ void body(int slice, int giw, int lane,
                                     const float* __restrict__ in,
                                     const float* __restrict__ anchors,
                                     float* __restrict__ out) {
    const int b  = slice / GG;
    const int gj = slice - b * GG;

    const float* __restrict__ src =
        in + (size_t)b * NROWS * PLANE + gj * GG + giw;
    float* __restrict__ dst =
        out + (size_t)slice * SLICE_N + (size_t)giw * NROWS;

    // preload anchors into regs (L1-uniform)
    const float a0x = anchors[0], a0y = anchors[1];
    const float a1x = anchors[2], a1y = anchors[3];
    const float a2x = anchors[4], a2y = anchors[5];
    const float gjf = (float)gj;

    #pragma unroll
    for (int it = 0; it < 4; ++it) {
        const int c = it * 64 + lane;          // 0..255; only (3,63) masked
        if (c < NROWS) {
            const int a    = (c >= 170) ? 2 : (c >= 85 ? 1 : 0);
            const int attr = c - a * 85;
            const float ax = (a == 0) ? a0x : (a == 1) ? a1x : a2x;
            const float ay = (a == 0) ? a0y : (a == 1) ? a1y : a2y;

            if constexpr (NGW == 4) {
                const f32x4 v =
                    *reinterpret_cast<const f32x4*>(src + (size_t)c * PLANE);
                #pragma unroll
                for (int k = 0; k < 4; ++k) {
                    const float x = v[k];
                    const float s = fast_sigmoid(x);
                    float r;
                    if (attr >= 4)      r = s;
                    else if (attr == 0) r = (s + (float)(giw + k)) * 8.0f;
                    else if (attr == 1) r = (s + gjf) * 8.0f;
                    else if (attr == 2) r = __builtin_amdgcn_exp2f(L2E * x) * ax;
                    else                r = __builtin_amdgcn_exp2f(L2E * x) * ay;
                    // contiguous 256B wave store per k
                    dst[(size_t)k * NROWS + c] = r;
                }
            } else {
                const float x = src[(size_t)c * PLANE];
                const float s = fast_sigmoid(x);
                float r;
                if (attr >= 4)      r = s;
                else if (attr == 0) r = (s + (float)giw) * 8.0f;
                else if (attr == 1) r = (s + gjf) * 8.0f;
                else if (attr == 2) r = __builtin_amdgcn_exp2f(L2E * x) * ax;
                else                r = __builtin_amdgcn_exp2f(L2E * x) * ay;
                dst[c] = r;
            }
        }
    }
}

__global__ __launch_bounds__(256, 8)
void detect_decode_kernel(const float* __restrict__ in,
                          const float* __restrict__ anchors,
                          float* __restrict__ out) {
    // XCD-bijective swizzle: grid = 6656 = 8*832; a slice's 4 chunks occupy
    // consecutive slots on the SAME xcd.
    const int B     = blockIdx.x;
    const int xcd   = B & 7;
    const int slot  = B >> 3;            // 0..831
    const int chunk = slot & 3;
    const int slice = ((slot >> 2) << 3) | xcd;   // 0..1663
    const int t     = threadIdx.x;
    const int w     = t >> 6;            // wave 0..3
    const int l     = t & 63;

    if (chunk < 3)
        body<4>(slice, chunk * 16 + w * 4, l, in, anchors, out);
    else
        body<1>(slice, 48 + w, l, in, anchors, out);
}

extern "C" void kernel_launch(void* const* d_in, const int* in_sizes, int n_in,
                              void* d_out, int out_size, void* d_ws, size_t ws_size,
                              hipStream_t stream) {
    const float* pred    = (const float*)d_in[0];
    const float* anchors = (const float*)d_in[1];
    float* out = (float*)d_out;

    const int nblocks = BB * GG * 4;   // 6656
    detect_decode_kernel<<<nblocks, 256, 0, stream>>>(pred, anchors, out);
}

// Round 10
// 43.310 us; speedup vs baseline: 1.0685x; 1.0685x over previous
//
#include <hip/hip_runtime.h>
#include <math.h>

// YOLOv3 detection-head decode — aligned-burst reads, merged streaming writes.
// prediction: [B=32, 255, 52, 52] f32 ; anchors: [3,2] f32
// out: [B, 52*52*3, 85] f32 ; out elem = (b*2704 + s)*255 + c, s = gj*52+gi.
//
// Block = (b, gjq, c-chunk), gjq = group of 4 consecutive gj.
//   Read : per row c, segment in[b][c][gjq*208 .. +208) = 832B = EXACTLY 13
//          aligned 64B lines (2704*4 and 208*4 are line multiples). 64 rows
//          per block, row-exclusive -> zero partial lines, zero overlap, 4x
//          longer DRAM bursts than any prior round.
//   LDS  : tile[c_l][S], S = gj_l*52+gi in [0,208) — input segment order IS
//          output spatial order. Stride 210 floats (rows 8B-aligned -> b64
//          writes; write-phase scalar reads ~4-way = cheap).
//   Write: lane owns (S, c_l): each wave store = contiguous 256B stream;
//          block covers all S for its c-range; the 4 c-chunks of a (b,gjq)
//          sit consecutively on the SAME XCD (swizzle) so L2 merges their
//          interleaved streams into full lines.
// 1024 thr, LDS 53,760B -> 2 blocks/CU; grid 1664 = 8 xcd * 4 chunk * 52.

#define GG 52
#define NROWS 255
#define PLANE 2704             // 52*52
#define L2E 1.442695040889f
#define P 210                  // LDS row stride (floats), rows 8B-aligned

typedef float f32x4 __attribute__((ext_vector_type(4)));
typedef float f32x2 __attribute__((ext_vector_type(2)));

__device__ __forceinline__ float fast_sigmoid(float x) {
    return __builtin_amdgcn_rcpf(1.0f + __builtin_amdgcn_exp2f(-L2E * x));
}

__global__ __launch_bounds__(1024, 8)
void detect_decode_kernel(const float* __restrict__ in,
                          const float* __restrict__ anchors,
                          float* __restrict__ out) {
    __shared__ float tile[64 * P];      // 53,760 B

    // swizzle: all 4 c-chunks of a (b,gjq) unit consecutive on one XCD
    const int B     = blockIdx.x;       // 1664
    const int xcd   = B & 7;
    const int slot  = B >> 3;           // 0..207
    const int chunk = slot & 3;
    const int u     = (slot >> 2) * 8 + xcd;   // 0..415
    const int b     = u / 13;
    const int gjq   = u - b * 13;
    const int t     = threadIdx.x;

    const int c0 = chunk * 64;
    const int CL = (chunk == 3) ? 63 : 64;     // rows in this chunk

    // ---- load: CL rows x 52 float4 = 832B aligned bursts ----
    const float* __restrict__ src =
        in + (size_t)(b * NROWS + c0) * PLANE + gjq * 208;

    #pragma unroll
    for (int it = 0; it < 4; ++it) {
        const int idx = t + it * 1024;         // 3328 (or 3276) float4 total
        if (idx < CL * 52) {
            const int row = idx / 52;          // magic div
            const int s4  = idx - row * 52;
            const f32x4 v = *reinterpret_cast<const f32x4*>(
                src + (size_t)row * PLANE + 4 * s4);
            const int l = row * P + 4 * s4;    // even -> 8B aligned
            *reinterpret_cast<f32x2*>(&tile[l])     = f32x2{v.x, v.y};
            *reinterpret_cast<f32x2*>(&tile[l + 2]) = f32x2{v.z, v.w};
        }
    }

    __syncthreads();

    // anchors in regs
    const float a0x = anchors[0], a0y = anchors[1];
    const float a1x = anchors[2], a1y = anchors[3];
    const float a2x = anchors[4], a2y = anchors[5];

    // ---- write: lane = (S, c_l); wave = contiguous 256B stream ----
    float* __restrict__ dst =
        out + (size_t)(b * PLANE + gjq * 208) * NROWS;

    #pragma unroll 4
    for (int it = 0; it < 13; ++it) {          // 13*1024 = 208*64 slots
        const int idx = t + it * 1024;
        const int c_l = idx & 63;
        const int S   = idx >> 6;              // 0..207
        if (c_l < CL) {
            const int c    = c0 + c_l;
            const int a    = (c >= 170) ? 2 : (c >= 85 ? 1 : 0);
            const int attr = c - a * 85;

            const float x = tile[c_l * P + S];
            const float s = fast_sigmoid(x);

            const int gj_l = S / 52;           // magic div
            const int gi   = S - gj_l * 52;

            float r;
            if (attr >= 4)      r = s;
            else if (attr == 0) r = (s + (float)gi) * 8.0f;
            else if (attr == 1) r = (s + (float)(gjq * 4 + gj_l)) * 8.0f;
            else {
                const float anc =
                    (attr == 2) ? ((a == 0) ? a0x : (a == 1) ? a1x : a2x)
                                : ((a == 0) ? a0y : (a == 1) ? a1y : a2y);
                r = __builtin_amdgcn_exp2f(L2E * x) * anc;
            }
            dst[S * NROWS + c] = r;
        }
    }
}

extern "C" void kernel_launch(void* const* d_in, const int* in_sizes, int n_in,
                              void* d_out, int out_size, void* d_ws, size_t ws_size,
                              hipStream_t stream) {
    const float* pred    = (const float*)d_in[0];
    const float* anchors = (const float*)d_in[1];
    float* out = (float*)d_out;

    const int nblocks = 8 * 4 * 52;    // 1664 = xcd * chunk * units-per-xcd
    detect_decode_kernel<<<nblocks, 1024, 0, stream>>>(pred, anchors, out);
}

// Round 11
// 38.436 us; speedup vs baseline: 1.2039x; 1.1268x over previous
//
#include <hip/hip_runtime.h>
#include <math.h>

// YOLOv3 detection-head decode — fully 64B-line-aligned tiling.
// prediction: [B=32, 255, 52, 52] f32 ; anchors: [3,2] f32
// out: [B, 52*52*3, 85] f32 ; flat out elem = (b*2704 + s)*255 + c,
// s = gj*52 + gi, c = a*85 + attr.
//
// Unit = 16 consecutive s (s0 = 16*grp): 16*255*4B = 16,320B = EXACTLY 255
// aligned 64B lines on the output, and in[b][c][s0..s0+16) = ONE aligned
// 64B line per c on the input (plane is flat s; 2704%16==0 so no b straddle).
// Block = one unit:
//   Load : 255 exclusive aligned full lines (4 x float4 per c) -> LDS in
//          output order e=(s-s0)*255+c (16,320B -> 8 blocks/CU).
//   Write: 1020 float4 = one contiguous, line-aligned, exclusive 16,320B
//          NT stream; full attr decode in-register (VALU has headroom, R8).
// Zero partial lines, zero RMW, zero cross-block write sharing, 1 barrier.
// XCD swizzle: each XCD owns a contiguous grp-range (adjacent groups read
// adjacent lines of the same input rows -> L2/DRAM-row locality).

#define GG 52
#define NROWS 255
#define PLANE 2704             // 52*52, flat s
#define NGRP 5408              // 32 * 169 groups of 16 s
#define L2E 1.442695040889f

typedef float f32x4 __attribute__((ext_vector_type(4)));

__device__ __forceinline__ float fast_sigmoid(float x) {
    return __builtin_amdgcn_rcpf(1.0f + __builtin_amdgcn_exp2f(-L2E * x));
}

__global__ __launch_bounds__(256, 8)
void detect_decode_kernel(const float* __restrict__ in,
                          const float* __restrict__ anchors,
                          float* __restrict__ out) {
    __shared__ float tile[16 * NROWS];   // 16,320 B, output order

    // XCD swizzle: XCD x owns contiguous grp range [x*676, (x+1)*676)
    const int B   = blockIdx.x;
    const int g   = (B & 7) * (NGRP / 8) + (B >> 3);   // 0..5407
    const int b   = g / 169;
    const int s0  = (g - b * 169) * 16;                // within-plane s base
    const int t   = threadIdx.x;

    const float* __restrict__ src = in + (size_t)b * NROWS * PLANE + s0;

    // ---- load: 255 c-rows x one 64B line (4 float4), scatter to LDS ----
    #pragma unroll
    for (int it = 0; it < 4; ++it) {
        const int idx = t + it * 256;          // 0..1019 (1020 = 255*4)
        if (idx < NROWS * 4) {
            const int c = idx >> 2;
            const int q = idx & 3;
            const f32x4 v = *reinterpret_cast<const f32x4*>(
                src + (size_t)c * PLANE + 4 * q);
            const int e = (4 * q) * NROWS + c; // e = s_l*255 + c
            tile[e            ] = v.x;
            tile[e +     NROWS] = v.y;
            tile[e + 2 * NROWS] = v.z;
            tile[e + 3 * NROWS] = v.w;
        }
    }

    __syncthreads();

    const float a0x = anchors[0], a0y = anchors[1];
    const float a1x = anchors[2], a1y = anchors[3];
    const float a2x = anchors[4], a2y = anchors[5];

    // ---- write: 1020 float4, contiguous line-aligned NT stream ----
    float* __restrict__ dst = out + ((size_t)b * PLANE + s0) * NROWS;

    #pragma unroll
    for (int it = 0; it < 4; ++it) {
        const int i = t + it * 256;
        if (i < NROWS * 4) {
            const f32x4 u = *reinterpret_cast<const f32x4*>(&tile[4 * i]);
            const int e0  = 4 * i;

            float r[4];
            #pragma unroll
            for (int k = 0; k < 4; ++k) {
                const int e   = e0 + k;
                const int s_l = e / NROWS;             // magic div, 0..15
                const int c   = e - s_l * NROWS;
                const int a    = (c >= 170) ? 2 : (c >= 85 ? 1 : 0);
                const int attr = c - a * 85;
                const int s    = s0 + s_l;
                const int gj   = s / GG;               // magic div
                const int gi   = s - gj * GG;

                const float x  = (k == 0) ? u.x : (k == 1) ? u.y
                               : (k == 2) ? u.z : u.w;
                const float sg = fast_sigmoid(x);
                const float ex = __builtin_amdgcn_exp2f(L2E * x);
                const float ancx = (a == 0) ? a0x : (a == 1) ? a1x : a2x;
                const float ancy = (a == 0) ? a0y : (a == 1) ? a1y : a2y;

                float r_;
                if (attr >= 4)      r_ = sg;
                else if (attr == 0) r_ = (sg + (float)gi) * 8.0f;
                else if (attr == 1) r_ = (sg + (float)gj) * 8.0f;
                else if (attr == 2) r_ = ex * ancx;
                else                r_ = ex * ancy;
                r[k] = r_;
            }

            f32x4 o; o.x = r[0]; o.y = r[1]; o.z = r[2]; o.w = r[3];
            __builtin_nontemporal_store(o, reinterpret_cast<f32x4*>(dst + 4 * i));
        }
    }
}

extern "C" void kernel_launch(void* const* d_in, const int* in_sizes, int n_in,
                              void* d_out, int out_size, void* d_ws, size_t ws_size,
                              hipStream_t stream) {
    const float* pred    = (const float*)d_in[0];
    const float* anchors = (const float*)d_in[1];
    float* out = (float*)d_out;

    detect_decode_kernel<<<NGRP, 256, 0, stream>>>(pred, anchors, out);
}

// Round 12
// 37.732 us; speedup vs baseline: 1.2264x; 1.0187x over previous
//
#include <hip/hip_runtime.h>
#include <math.h>

// YOLOv3 detection-head decode — R11 line-aligned tiling + explicit MLP.
// prediction: [B=32, 255, 52, 52] f32 ; anchors: [3,2] f32
// out: [B, 52*52*3, 85] f32 ; flat out elem = (b*2704 + s)*255 + c.
//
// Unit = 16 consecutive s: input = one aligned 64B line per c-row (255
// exclusive lines); output = 4080 contiguous floats (255 aligned lines).
// R12 change vs R11: guards -> clamps, and BOTH phases explicitly stage all
// 4 float4 into named registers before consuming (R11 compiled to 8 VGPRs =
// zero memory-level parallelism; the serial chain was the residual limiter).
// Plain stores (drop NT) to let L3 absorb the write stream if it can.

#define GG 52
#define NROWS 255
#define PLANE 2704             // 52*52, flat s
#define NGRP 5408              // 32 * 169 groups of 16 s
#define L2E 1.442695040889f

typedef float f32x4 __attribute__((ext_vector_type(4)));

__device__ __forceinline__ float fast_sigmoid(float x) {
    return __builtin_amdgcn_rcpf(1.0f + __builtin_amdgcn_exp2f(-L2E * x));
}

__device__ __forceinline__ void scatter(float* __restrict__ tile, int idx,
                                        f32x4 v) {
    // element (c = idx>>2, s_l = 4*(idx&3)+k) -> e = s_l*255 + c
    const int e = (idx & 3) * 4 * NROWS + (idx >> 2);
    tile[e            ] = v.x;
    tile[e +     NROWS] = v.y;
    tile[e + 2 * NROWS] = v.z;
    tile[e + 3 * NROWS] = v.w;
}

__device__ __forceinline__ f32x4 decode4(f32x4 u, int j, int s0, int gj0_,
                                         const float* __restrict__ anc) {
    const int e0  = 4 * j;
    const int sl0 = e0 / NROWS;            // magic div, 0..15
    const int c00 = e0 - sl0 * NROWS;
    f32x4 o;
    #pragma unroll
    for (int k = 0; k < 4; ++k) {
        const int wrap = (c00 + k >= NROWS) ? 1 : 0;
        const int c    = c00 + k - (wrap ? NROWS : 0);
        const int s_l  = sl0 + wrap;
        const int a    = (c >= 170) ? 2 : (c >= 85 ? 1 : 0);
        const int attr = c - a * 85;
        const int s    = s0 + s_l;
        const int gj   = s / GG;           // magic div
        const int gi   = s - gj * GG;

        const float x  = (k == 0) ? u.x : (k == 1) ? u.y : (k == 2) ? u.z : u.w;
        const float sg = fast_sigmoid(x);

        float r;
        if (attr >= 4)      r = sg;
        else if (attr == 0) r = (sg + (float)gi) * 8.0f;
        else if (attr == 1) r = (sg + (float)gj) * 8.0f;
        else                r = __builtin_amdgcn_exp2f(L2E * x)
                                * anc[a * 2 + (attr & 1)];
        if (k == 0) o.x = r; else if (k == 1) o.y = r;
        else if (k == 2) o.z = r; else o.w = r;
    }
    return o;
}

__global__ __launch_bounds__(256, 8)
void detect_decode_kernel(const float* __restrict__ in,
                          const float* __restrict__ anchors,
                          float* __restrict__ out) {
    __shared__ float tile[16 * NROWS];   // 16,320 B, output order

    // XCD swizzle: XCD x owns contiguous grp range (adjacent groups share
    // input-line neighborhoods in one L2)
    const int B   = blockIdx.x;
    const int g   = (B & 7) * (NGRP / 8) + (B >> 3);   // 0..5407
    const int b   = g / 169;
    const int s0  = (g - b * 169) * 16;
    const int t   = threadIdx.x;

    const float* __restrict__ src = in + (size_t)b * NROWS * PLANE + s0;

    // ---- load: stage 4 float4 (named regs -> 4-deep MLP), then scatter ----
    const int i0 = t;
    const int i1 = t + 256;
    const int i2 = t + 512;
    const int i3 = (t + 768 < 1020) ? t + 768 : 1019;   // clamp, no guard

    const f32x4 v0 = *reinterpret_cast<const f32x4*>(src + (size_t)(i0 >> 2) * PLANE + (i0 & 3) * 4);
    const f32x4 v1 = *reinterpret_cast<const f32x4*>(src + (size_t)(i1 >> 2) * PLANE + (i1 & 3) * 4);
    const f32x4 v2 = *reinterpret_cast<const f32x4*>(src + (size_t)(i2 >> 2) * PLANE + (i2 & 3) * 4);
    const f32x4 v3 = *reinterpret_cast<const f32x4*>(src + (size_t)(i3 >> 2) * PLANE + (i3 & 3) * 4);

    scatter(tile, i0, v0);
    scatter(tile, i1, v1);
    scatter(tile, i2, v2);
    scatter(tile, i3, v3);   // clamped lanes rewrite identical values: benign

    __syncthreads();

    // anchors in regs
    const float anc[6] = {anchors[0], anchors[1], anchors[2],
                          anchors[3], anchors[4], anchors[5]};

    // ---- write: stage 4 ds_read_b128, then decode + 4 contiguous stores ----
    float* __restrict__ dst = out + ((size_t)b * PLANE + s0) * NROWS;

    const f32x4 u0 = *reinterpret_cast<const f32x4*>(&tile[4 * i0]);
    const f32x4 u1 = *reinterpret_cast<const f32x4*>(&tile[4 * i1]);
    const f32x4 u2 = *reinterpret_cast<const f32x4*>(&tile[4 * i2]);
    const f32x4 u3 = *reinterpret_cast<const f32x4*>(&tile[4 * i3]);

    *reinterpret_cast<f32x4*>(dst + 4 * i0) = decode4(u0, i0, s0, 0, anc);
    *reinterpret_cast<f32x4*>(dst + 4 * i1) = decode4(u1, i1, s0, 0, anc);
    *reinterpret_cast<f32x4*>(dst + 4 * i2) = decode4(u2, i2, s0, 0, anc);
    *reinterpret_cast<f32x4*>(dst + 4 * i3) = decode4(u3, i3, s0, 0, anc);
}

extern "C" void kernel_launch(void* const* d_in, const int* in_sizes, int n_in,
                              void* d_out, int out_size, void* d_ws, size_t ws_size,
                              hipStream_t stream) {
    const float* pred    = (const float*)d_in[0];
    const float* anchors = (const float*)d_in[1];
    float* out = (float*)d_out;

    detect_decode_kernel<<<NGRP, 256, 0, stream>>>(pred, anchors, out);
}

// Round 13
// 33.670 us; speedup vs baseline: 1.3744x; 1.1206x over previous
//
#include <hip/hip_runtime.h>
#include <math.h>

// YOLOv3 detection-head decode — line-aligned tiling (R11) x branch-free
// bulk + fixup (R8). prediction: [B=32,255,52,52] f32; anchors: [3,2] f32
// out: [B, 52*52*3, 85] f32 ; flat out elem = (b*2704 + s)*255 + c.
//
// Unit = 16 consecutive s: input = one aligned 64B line per c-row (255
// exclusive lines); output = 4080 contiguous floats (255 aligned lines).
//   Load : 255 lines -> LDS in output order (16,320B, 8 blocks/CU).
//   Bulk : branch-free: 4x ds_read_b128 -> 16 sigmoids -> 4 PLAIN dwordx4
//          stores (no decode: 251/255 columns are plain sigmoid).
//   Fixup: after __syncthreads (vmcnt drained -> stores ordered in L2),
//          192 threads recompute x/y/w/h columns from the intact LDS tile
//          and overwrite 4B each onto L2-dirty lines (no HBM RMW).
// XCD swizzle: each XCD owns a contiguous group range.

#define GG 52
#define NROWS 255
#define PLANE 2704             // 52*52, flat s
#define NGRP 5408              // 32 * 169 groups of 16 s
#define L2E 1.442695040889f

typedef float f32x4 __attribute__((ext_vector_type(4)));

__device__ __forceinline__ float fast_sigmoid(float x) {
    return __builtin_amdgcn_rcpf(1.0f + __builtin_amdgcn_exp2f(-L2E * x));
}

__device__ __forceinline__ void scatter(float* __restrict__ tile, int idx,
                                        f32x4 v) {
    // element (c = idx>>2, s_l = 4*(idx&3)+k) -> e = s_l*255 + c
    const int e = (idx & 3) * 4 * NROWS + (idx >> 2);
    tile[e            ] = v.x;
    tile[e +     NROWS] = v.y;
    tile[e + 2 * NROWS] = v.z;
    tile[e + 3 * NROWS] = v.w;
}

__device__ __forceinline__ f32x4 sig4(f32x4 u) {
    f32x4 o;
    o.x = fast_sigmoid(u.x);
    o.y = fast_sigmoid(u.y);
    o.z = fast_sigmoid(u.z);
    o.w = fast_sigmoid(u.w);
    return o;
}

__global__ __launch_bounds__(256, 8)
void detect_decode_kernel(const float* __restrict__ in,
                          const float* __restrict__ anchors,
                          float* __restrict__ out) {
    __shared__ float tile[16 * NROWS];   // 16,320 B, output order

    // XCD swizzle: XCD x owns contiguous grp range
    const int B   = blockIdx.x;
    const int g   = (B & 7) * (NGRP / 8) + (B >> 3);   // 0..5407
    const int b   = g / 169;
    const int s0  = (g - b * 169) * 16;
    const int t   = threadIdx.x;

    const float* __restrict__ src = in + (size_t)b * NROWS * PLANE + s0;

    // ---- load: 255 exclusive aligned lines -> output-order LDS ----
    const int i0 = t;
    const int i1 = t + 256;
    const int i2 = t + 512;
    const int i3 = (t + 768 < 1020) ? t + 768 : 1019;   // clamp, no guard

    const f32x4 v0 = *reinterpret_cast<const f32x4*>(src + (size_t)(i0 >> 2) * PLANE + (i0 & 3) * 4);
    const f32x4 v1 = *reinterpret_cast<const f32x4*>(src + (size_t)(i1 >> 2) * PLANE + (i1 & 3) * 4);
    const f32x4 v2 = *reinterpret_cast<const f32x4*>(src + (size_t)(i2 >> 2) * PLANE + (i2 & 3) * 4);
    const f32x4 v3 = *reinterpret_cast<const f32x4*>(src + (size_t)(i3 >> 2) * PLANE + (i3 & 3) * 4);

    scatter(tile, i0, v0);
    scatter(tile, i1, v1);
    scatter(tile, i2, v2);
    scatter(tile, i3, v3);   // clamped lanes rewrite identical values: benign

    __syncthreads();

    // ---- bulk: branch-free sigmoid stream, plain stores ----
    float* __restrict__ dst = out + ((size_t)b * PLANE + s0) * NROWS;

    const f32x4 u0 = *reinterpret_cast<const f32x4*>(&tile[4 * i0]);
    const f32x4 u1 = *reinterpret_cast<const f32x4*>(&tile[4 * i1]);
    const f32x4 u2 = *reinterpret_cast<const f32x4*>(&tile[4 * i2]);
    const f32x4 u3 = *reinterpret_cast<const f32x4*>(&tile[4 * i3]);

    *reinterpret_cast<f32x4*>(dst + 4 * i0) = sig4(u0);
    *reinterpret_cast<f32x4*>(dst + 4 * i1) = sig4(u1);
    *reinterpret_cast<f32x4*>(dst + 4 * i2) = sig4(u2);
    *reinterpret_cast<f32x4*>(dst + 4 * i3) = sig4(u3);

    // order bulk stores (vmcnt drained at barrier) before fixup overwrites
    __syncthreads();

    // ---- fixup: 12 special columns x 16 s, 4B overwrites in L2 ----
    const int s_l = t >> 4;            // 0..15
    const int j   = t & 15;            // active if j < 12
    if (j < 12) {
        const int a    = j >> 2;       // 0..2
        const int attr = j & 3;        // 0..3
        const int c    = a * 85 + attr;
        const int e    = s_l * NROWS + c;
        const float x  = tile[e];      // tile still holds raw inputs

        const int s  = s0 + s_l;
        const int gj = s / GG;         // magic div
        const int gi = s - gj * GG;

        float r;
        if (attr == 0)      r = (fast_sigmoid(x) + (float)gi) * 8.0f;
        else if (attr == 1) r = (fast_sigmoid(x) + (float)gj) * 8.0f;
        else                r = __builtin_amdgcn_exp2f(L2E * x)
                                * anchors[a * 2 + (attr & 1)];
        dst[e] = r;
    }
}

extern "C" void kernel_launch(void* const* d_in, const int* in_sizes, int n_in,
                              void* d_out, int out_size, void* d_ws, size_t ws_size,
                              hipStream_t stream) {
    const float* pred    = (const float*)d_in[0];
    const float* anchors = (const float*)d_in[1];
    float* out = (float*)d_out;

    detect_decode_kernel<<<NGRP, 256, 0, stream>>>(pred, anchors, out);
}